// Round 1
// baseline (422.896 us; speedup 1.0000x reference)
//
#include <hip/hip_runtime.h>

#define B_SZ 256
#define C_SZ 1152
#define M_SZ 8
#define O_SZ 16
#define I_SZ 8
#define CAPS_EPS 1e-8f

// One routing pass. grid = B (one block per batch element), block = 256
// threads = 32 capsule-groups x 8 m-lanes. R = routing iteration (0,1,2).
//
// R=0: c uniform (softmax of zeros) -> s_out
// R=1: v0 = squash(s_in); logits = u_hat . v0; s_out; v0_out = v0
// R=2: v1 = squash(s_in); vsum = v0_in + v1; logits = u_hat . vsum;
//      out = squash(s_2)   [uses b linearity: b_2 = u_hat.(v0+v1)]
template <int R>
__global__ __launch_bounds__(256) void caps_pass(
    const float* __restrict__ u,      // [B, C, I]
    const float* __restrict__ W,      // [C, M, O, I]
    const float* __restrict__ s_in,   // [B, M, O] (R>=1)
    const float* __restrict__ v0_in,  // [B, M, O] (R==2)
    float* __restrict__ s_out,        // [B, M, O] (R<2)
    float* __restrict__ v0_out,       // [B, M, O] (R==1)
    float* __restrict__ out)          // [B, M, O] (R==2)
{
    const int b   = blockIdx.x;
    const int tid = threadIdx.x;

    __shared__ float sh_v[M_SZ][O_SZ + 1];    // padded: avoid bank conflicts
    __shared__ float sh_part[256][O_SZ + 1];  // per-thread partial s

    // ---- squash(s_in) -> sh_v (the v used for this pass's logits) ----
    if (R >= 1) {
        if (tid < 128) {  // waves 0,1 fully active
            float val = s_in[b * 128 + tid];
            float n2 = val * val;
            n2 += __shfl_xor(n2, 1);
            n2 += __shfl_xor(n2, 2);
            n2 += __shfl_xor(n2, 4);
            n2 += __shfl_xor(n2, 8);   // 16-lane group = one m row
            float norm = sqrtf(n2);
            float v = (n2 / (1.f + n2)) * val / (norm + CAPS_EPS);
            int m = tid >> 4, o = tid & 15;
            if (R == 1) {
                v0_out[b * 128 + tid] = v;
                sh_v[m][o] = v;
            } else {
                sh_v[m][o] = v + v0_in[b * 128 + tid];  // vsum = v0 + v1
            }
        }
        __syncthreads();
    }

    const int c_local = tid >> 3;  // 0..31
    const int m       = tid & 7;

    float s_acc[O_SZ];
#pragma unroll
    for (int o = 0; o < O_SZ; ++o) s_acc[o] = 0.f;

    for (int cc = 0; cc < C_SZ; cc += 32) {
        const int c = cc + c_local;

        // u[b,c,0:8] -- two float4 loads (8 lanes of a c-group hit same line)
        const float4* up = reinterpret_cast<const float4*>(
            u + (size_t)(b * C_SZ + c) * I_SZ);
        float4 u0 = up[0], u1 = up[1];
        float u8[8] = {u0.x, u0.y, u0.z, u0.w, u1.x, u1.y, u1.z, u1.w};

        // u_hat[c,m,o] for o = 0..15 (W[c,m] is 128 contiguous floats)
        float uh[O_SZ];
        const float4* wp = reinterpret_cast<const float4*>(
            W + (size_t)((c * M_SZ + m) * O_SZ) * I_SZ);
#pragma unroll
        for (int o = 0; o < O_SZ; ++o) {
            float4 w0 = wp[o * 2], w1 = wp[o * 2 + 1];
            uh[o] = w0.x * u8[0] + w0.y * u8[1] + w0.z * u8[2] + w0.w * u8[3] +
                    w1.x * u8[4] + w1.y * u8[5] + w1.z * u8[6] + w1.w * u8[7];
        }

        float cw;
        if (R == 0) {
            cw = 0.125f;  // softmax of zeros over M=8
        } else {
            float uv = 0.f;
#pragma unroll
            for (int o = 0; o < O_SZ; ++o) uv = fmaf(uh[o], sh_v[m][o], uv);
            // softmax over the 8 m-lanes of this capsule (8 consecutive lanes)
            float mx = uv;
            mx = fmaxf(mx, __shfl_xor(mx, 1));
            mx = fmaxf(mx, __shfl_xor(mx, 2));
            mx = fmaxf(mx, __shfl_xor(mx, 4));
            float e = expf(uv - mx);
            float den = e;
            den += __shfl_xor(den, 1);
            den += __shfl_xor(den, 2);
            den += __shfl_xor(den, 4);
            cw = e / den;
        }

#pragma unroll
        for (int o = 0; o < O_SZ; ++o) s_acc[o] = fmaf(cw, uh[o], s_acc[o]);
    }

    // ---- block reduction over the 32 capsule groups ----
#pragma unroll
    for (int o = 0; o < O_SZ; ++o) sh_part[tid][o] = s_acc[o];
    __syncthreads();

    if (tid < 128) {
        const int m2 = tid >> 4, o2 = tid & 15;
        float s = 0.f;
#pragma unroll
        for (int g = 0; g < 32; ++g) s += sh_part[g * 8 + m2][o2];

        if (R < 2) {
            s_out[b * 128 + tid] = s;
        } else {
            float n2 = s * s;
            n2 += __shfl_xor(n2, 1);
            n2 += __shfl_xor(n2, 2);
            n2 += __shfl_xor(n2, 4);
            n2 += __shfl_xor(n2, 8);
            float norm = sqrtf(n2);
            out[b * 128 + tid] = (n2 / (1.f + n2)) * s / (norm + CAPS_EPS);
        }
    }
}

extern "C" void kernel_launch(void* const* d_in, const int* in_sizes, int n_in,
                              void* d_out, int out_size, void* d_ws, size_t ws_size,
                              hipStream_t stream) {
    const float* u = (const float*)d_in[0];  // [256,1152,8]
    const float* W = (const float*)d_in[1];  // [1152,8,16,8]
    float* out = (float*)d_out;              // [256,8,16]

    float* sA = (float*)d_ws;       // [B,M,O] = 32768 floats
    float* sB = sA + 32768;         // [B,M,O]
    float* v0 = sB + 32768;         // [B,M,O]
    // total ws use: 384 KB

    dim3 grid(B_SZ), block(256);
    caps_pass<0><<<grid, block, 0, stream>>>(u, W, nullptr, nullptr, sA, nullptr, nullptr);
    caps_pass<1><<<grid, block, 0, stream>>>(u, W, sA, nullptr, sB, v0, nullptr);
    caps_pass<2><<<grid, block, 0, stream>>>(u, W, sB, v0, nullptr, nullptr, out);
}